// Round 1
// baseline (639.106 us; speedup 1.0000x reference)
//
#include <hip/hip_runtime.h>

// CrossAttentionGAT — algebraically collapsed.
//
// mean(cross1) = mean(emb2) @ Wl + bl   (softmax col-sums == 1)
// mean(cross2) = mean(emb1) @ Wl + bl   (softmax row-sums == 1)
// mean(emb)    = (1/N) * sum_e alpha_e * h[src_e] + b
//              = (1/N) * sum_k g[head,k] * W[k, head*C+c] + b
//   with g[head,k] = sum_n w[n,head] x[n,k],  w[n,head] = sum_{e: src=n} alpha_e[head]
// a_src[n,head] = x[n,:] . u_src[head,:],  u_src[head,k] = sum_c att_src[head,c] W[k,head*C+c]

#define NN 8192
#define EE 262144
#define ET (EE + NN)          // edges + self loops = 270336
#define HH 8
#define NEG 0.2f

// ---------------- ws layout (floats) ----------------
// den  : 2 * NN*HH  (zeroed)
// wacc : 2 * NN*HH  (zeroed)
// g    : 2 * 1024   (zeroed)
// u    : 2 * 2048   (written before read)
// asrc : 2 * NN*HH
// adst : 2 * NN*HH
// memb : 2 * 1024
#define OFF_DEN   0
#define OFF_WACC  (2 * NN * HH)
#define OFF_G     (OFF_WACC + 2 * NN * HH)
#define OFF_U     (OFF_G + 2 * 1024)
#define OFF_ASRC  (OFF_U + 2 * 2048)
#define OFF_ADST  (OFF_ASRC + 2 * NN * HH)
#define OFF_MEMB  (OFF_ADST + 2 * NN * HH)
#define ZERO_BYTES ((size_t)(OFF_G + 2 * 1024) * sizeof(float))

// K1: u[graph][sd][head][k] = sum_c att[head][c] * W[k][head*128+c]
__global__ __launch_bounds__(256) void k_u(
    const float* __restrict__ W1, const float* __restrict__ as1, const float* __restrict__ ad1,
    const float* __restrict__ W2, const float* __restrict__ as2, const float* __restrict__ ad2,
    float* __restrict__ u) {
  int graph = blockIdx.x >> 1, sd = blockIdx.x & 1;
  const float* W = graph ? W2 : W1;
  const float* att = graph ? (sd ? ad2 : as2) : (sd ? ad1 : as1);
  float* uo = u + graph * 2048 + sd * 1024;
  for (int e = threadIdx.x; e < 1024; e += 256) {
    int head = e >> 7, k = e & 127;
    const float* wr = W + (size_t)k * 1024 + head * 128;
    const float* ar = att + head * 128;
    float s = 0.f;
#pragma unroll 8
    for (int c = 0; c < 128; ++c) s += wr[c] * ar[c];
    uo[e] = s;
  }
}

// K2: a_src[n,h] = x[n,:] . u_src[h,:] ; a_dst likewise. 64 nodes/block.
__global__ __launch_bounds__(256) void k_a(
    const float* __restrict__ x1, const float* __restrict__ x2,
    const float* __restrict__ u, float* __restrict__ asrc, float* __restrict__ adst) {
  int graph = blockIdx.y;
  const float* x = graph ? x2 : x1;
  const float* ug = u + graph * 2048;
  __shared__ float xs[64][129];   // +1 pad: lane-stride 129 % 32 == 1, conflict-free
  __shared__ float us[16][128];
  int t = threadIdx.x;
  for (int i = t; i < 2048; i += 256) us[i >> 7][i & 127] = ug[i];
  int n0 = blockIdx.x * 64;
  const float* xb = x + (size_t)n0 * 128;
  for (int i = t; i < 64 * 128; i += 256) xs[i >> 7][i & 127] = xb[i];
  __syncthreads();
  int nl = t & 63;
  int j0 = (t >> 6) * 4;          // 0,4,8,12 : wave-uniform -> us reads broadcast
  float a0 = 0.f, a1 = 0.f, a2 = 0.f, a3 = 0.f;
#pragma unroll 4
  for (int k = 0; k < 128; ++k) {
    float xv = xs[nl][k];
    a0 += xv * us[j0 + 0][k];
    a1 += xv * us[j0 + 1][k];
    a2 += xv * us[j0 + 2][k];
    a3 += xv * us[j0 + 3][k];
  }
  int n = n0 + nl;
  float* outp = (j0 < 8) ? (asrc + graph * (NN * HH) + n * 8 + j0)
                         : (adst + graph * (NN * HH) + n * 8 + (j0 - 8));
  outp[0] = a0; outp[1] = a1; outp[2] = a2; outp[3] = a3;
}

// K3: den[dst,h] += exp(leaky_relu(a_src[src,h] + a_dst[dst,h]))  (incl. self loops)
__global__ __launch_bounds__(256) void k_edge_den(
    const int* __restrict__ ei1, const int* __restrict__ ei2,
    const float* __restrict__ asrc, const float* __restrict__ adst,
    float* __restrict__ den) {
  int graph = blockIdx.y;
  const int* ei = graph ? ei2 : ei1;
  const float* as = asrc + graph * (NN * HH);
  const float* ad = adst + graph * (NN * HH);
  float* dn = den + graph * (NN * HH);
  int idx = blockIdx.x * 256 + threadIdx.x;
  if (idx >= ET) return;
  int s, d;
  if (idx < EE) { s = ei[idx]; d = ei[EE + idx]; } else { s = d = idx - EE; }
  const float4* a4 = (const float4*)(as + (size_t)s * 8);
  const float4* b4 = (const float4*)(ad + (size_t)d * 8);
  float4 al = a4[0], ah = a4[1], bl = b4[0], bh = b4[1];
  float e[8] = {al.x + bl.x, al.y + bl.y, al.z + bl.z, al.w + bl.w,
                ah.x + bh.x, ah.y + bh.y, ah.z + bh.z, ah.w + bh.w};
  float* dp = dn + (size_t)d * 8;
#pragma unroll
  for (int h = 0; h < 8; ++h) {
    float v = e[h];
    v = v > 0.f ? v : NEG * v;
    atomicAdd(dp + h, __expf(v));
  }
}

// K4: w[src,h] += exp(leaky_relu(...)) / den[dst,h]
__global__ __launch_bounds__(256) void k_edge_w(
    const int* __restrict__ ei1, const int* __restrict__ ei2,
    const float* __restrict__ asrc, const float* __restrict__ adst,
    const float* __restrict__ den, float* __restrict__ wacc) {
  int graph = blockIdx.y;
  const int* ei = graph ? ei2 : ei1;
  const float* as = asrc + graph * (NN * HH);
  const float* ad = adst + graph * (NN * HH);
  const float* dn = den + graph * (NN * HH);
  float* w = wacc + graph * (NN * HH);
  int idx = blockIdx.x * 256 + threadIdx.x;
  if (idx >= ET) return;
  int s, d;
  if (idx < EE) { s = ei[idx]; d = ei[EE + idx]; } else { s = d = idx - EE; }
  const float4* a4 = (const float4*)(as + (size_t)s * 8);
  const float4* b4 = (const float4*)(ad + (size_t)d * 8);
  const float4* d4 = (const float4*)(dn + (size_t)d * 8);
  float4 al = a4[0], ah = a4[1], bl = b4[0], bh = b4[1];
  float4 dl = d4[0], dh = d4[1];
  float e[8] = {al.x + bl.x, al.y + bl.y, al.z + bl.z, al.w + bl.w,
                ah.x + bh.x, ah.y + bh.y, ah.z + bh.z, ah.w + bh.w};
  float dv[8] = {dl.x, dl.y, dl.z, dl.w, dh.x, dh.y, dh.z, dh.w};
  float* wp = w + (size_t)s * 8;
#pragma unroll
  for (int h = 0; h < 8; ++h) {
    float v = e[h];
    v = v > 0.f ? v : NEG * v;
    atomicAdd(wp + h, __expf(v) / dv[h]);
  }
}

// K5: g[head,k] = sum_n w[n,head] * x[n,k].  thread: k = t&127, heads (t>>7)*4..+3
#define GCHUNK 128
__global__ __launch_bounds__(256) void k_gred(
    const float* __restrict__ x1, const float* __restrict__ x2,
    const float* __restrict__ wacc, float* __restrict__ g) {
  int graph = blockIdx.y;
  const float* x = graph ? x2 : x1;
  const float* w = wacc + graph * (NN * HH);
  float* gg = g + graph * 1024;
  int t = threadIdx.x;
  int k = t & 127;
  int h0 = (t >> 7) * 4;          // 0 or 4
  int n0 = blockIdx.x * GCHUNK;
  float a0 = 0.f, a1 = 0.f, a2 = 0.f, a3 = 0.f;
#pragma unroll 4
  for (int n = n0; n < n0 + GCHUNK; ++n) {
    float xv = x[(size_t)n * 128 + k];
    float4 wv = *(const float4*)(w + (size_t)n * 8 + h0);
    a0 += xv * wv.x; a1 += xv * wv.y; a2 += xv * wv.z; a3 += xv * wv.w;
  }
  atomicAdd(gg + (h0 + 0) * 128 + k, a0);
  atomicAdd(gg + (h0 + 1) * 128 + k, a1);
  atomicAdd(gg + (h0 + 2) * 128 + k, a2);
  atomicAdd(gg + (h0 + 3) * 128 + k, a3);
}

// K6: memb[graph][e] = (1/N) * sum_k g[head,k]*W[k*1024+e] + b[e],  e = head*128+c
__global__ __launch_bounds__(256) void k_memb(
    const float* __restrict__ W1, const float* __restrict__ W2,
    const float* __restrict__ b1, const float* __restrict__ b2,
    const float* __restrict__ g, float* __restrict__ memb) {
  int graph = blockIdx.y;
  const float* W = graph ? W2 : W1;
  const float* b = graph ? b2 : b1;
  const float* gg = g + graph * 1024;
  int e = blockIdx.x * 256 + threadIdx.x;
  int head = e >> 7;
  const float* gr = gg + head * 128;
  float s = 0.f;
#pragma unroll 4
  for (int k = 0; k < 128; ++k) s += gr[k] * W[(size_t)k * 1024 + e];
  memb[graph * 1024 + e] = s * (1.0f / (float)NN) + b[e];
}

// K7: out[0:128] = memb(graph1) @ Wl + bl ; out[128:256] = memb(graph0) @ Wl + bl
__global__ __launch_bounds__(256) void k_out(
    const float* __restrict__ memb, const float* __restrict__ Wl,
    const float* __restrict__ bl, float* __restrict__ out) {
  int t = threadIdx.x;
  int j = t & 127;
  const float* m = (t < 128) ? (memb + 1024) : memb;
  float s = 0.f;
#pragma unroll 4
  for (int k = 0; k < 1024; ++k) s += m[k] * Wl[(size_t)k * 128 + j];
  out[t] = s + bl[j];
}

extern "C" void kernel_launch(void* const* d_in, const int* in_sizes, int n_in,
                              void* d_out, int out_size, void* d_ws, size_t ws_size,
                              hipStream_t stream) {
  const float* x1  = (const float*)d_in[0];
  const int*   ei1 = (const int*)d_in[1];
  const float* W1  = (const float*)d_in[2];
  const float* as1 = (const float*)d_in[3];
  const float* ad1 = (const float*)d_in[4];
  const float* b1  = (const float*)d_in[5];
  const float* x2  = (const float*)d_in[6];
  const int*   ei2 = (const int*)d_in[7];
  const float* W2  = (const float*)d_in[8];
  const float* as2 = (const float*)d_in[9];
  const float* ad2 = (const float*)d_in[10];
  const float* b2  = (const float*)d_in[11];
  const float* Wl  = (const float*)d_in[12];
  const float* bl  = (const float*)d_in[13];
  float* out = (float*)d_out;

  float* ws   = (float*)d_ws;
  float* den  = ws + OFF_DEN;
  float* wacc = ws + OFF_WACC;
  float* g    = ws + OFF_G;
  float* u    = ws + OFF_U;
  float* asrc = ws + OFF_ASRC;
  float* adst = ws + OFF_ADST;
  float* memb = ws + OFF_MEMB;

  hipMemsetAsync(d_ws, 0, ZERO_BYTES, stream);   // den, wacc, g

  k_u<<<4, 256, 0, stream>>>(W1, as1, ad1, W2, as2, ad2, u);
  k_a<<<dim3(NN / 64, 2), 256, 0, stream>>>(x1, x2, u, asrc, adst);
  k_edge_den<<<dim3((ET + 255) / 256, 2), 256, 0, stream>>>(ei1, ei2, asrc, adst, den);
  k_edge_w<<<dim3((ET + 255) / 256, 2), 256, 0, stream>>>(ei1, ei2, asrc, adst, den, wacc);
  k_gred<<<dim3(NN / GCHUNK, 2), 256, 0, stream>>>(x1, x2, wacc, g);
  k_memb<<<dim3(4, 2), 256, 0, stream>>>(W1, W2, b1, b2, g, memb);
  k_out<<<1, 256, 0, stream>>>(memb, Wl, bl, out);
}

// Round 2
// 234.498 us; speedup vs baseline: 2.7254x; 2.7254x over previous
//
#include <hip/hip_runtime.h>

// CrossAttentionGAT — algebraically collapsed + counting-sort edge path.
//
// mean(cross1) = mean(emb2) @ Wl + bl   (softmax col-sums == 1)
// mean(cross2) = mean(emb1) @ Wl + bl   (softmax row-sums == 1)
// mean(emb)    = (1/N) * sum_k g[head,k] * W[k, head*C+c] + b
//   g[head,k]  = sum_n w[n,head] x[n,k],  w[n,head] = sum_{e: src=n} alpha_e[head]
// Edge path: counting-sort edges by dst (for den) and by src (for w),
// then atomic-free wave-per-node segment reductions. Int sort atomics
// (2.16M tx) replace float scatter atomics (8.6M tx @ ~19.5 tx/cyc cap).

#define NN 8192
#define EE 262144
#define ET (EE + NN)          // edges + self loops = 270336
#define NEG 0.2f
#define OFFPAD 8196           // 8193 rounded up to keep 16B alignment downstream

// ---------------- ws layout (4-byte units) ----------------
#define U_CNT   0                      // 4*NN ints: cntD g0, cntS g0, cntD g1, cntS g1  (zeroed)
#define U_G     (U_CNT + 4*NN)         // 2*1024 floats (zeroed)
#define U_ZEND  (U_G + 2048)           // zero region end
#define U_CUR   (U_ZEND)               // 4*NN ints (cursors, written by scan)
#define U_OFF   (U_CUR + 4*NN)         // 4*OFFPAD ints (offsets)
#define U_SORT  (U_OFF + 4*OFFPAD)     // 4*ET ints: srcByDst g0, dstBySrc g0, srcByDst g1, dstBySrc g1
#define U_ASRC  (U_SORT + 4*ET)        // 2*NN*8 floats
#define U_ADST  (U_ASRC + 2*NN*8)
#define U_RDEN  (U_ADST + 2*NN*8)      // reciprocal denominators
#define U_WACC  (U_RDEN + 2*NN*8)
#define U_U     (U_WACC + 2*NN*8)      // 2*2048 floats
#define U_MEMB  (U_U + 2*2048)         // 2*1024 floats
#define ZERO_BYTES ((size_t)U_ZEND * 4)

// K1: u[graph][sd][head][k] = sum_c att[head][c] * W[k][head*128+c].  16 blocks.
__global__ __launch_bounds__(256) void k_u(
    const float* __restrict__ W1, const float* __restrict__ as1, const float* __restrict__ ad1,
    const float* __restrict__ W2, const float* __restrict__ as2, const float* __restrict__ ad2,
    float* __restrict__ u) {
  int grp = blockIdx.x >> 2;           // graph*2+sd
  int q = blockIdx.x & 3;
  int graph = grp >> 1, sd = grp & 1;
  const float* W = graph ? W2 : W1;
  const float* att = graph ? (sd ? ad2 : as2) : (sd ? ad1 : as1);
  float* uo = u + graph * 2048 + sd * 1024;
  int e = q * 256 + threadIdx.x;       // 0..1023
  int head = e >> 7, k = e & 127;
  const float* wr = W + (size_t)k * 1024 + head * 128;
  const float* ar = att + head * 128;
  float s = 0.f;
#pragma unroll 8
  for (int c = 0; c < 128; ++c) s += wr[c] * ar[c];
  uo[e] = s;
}

// K2: a_src[n,h] = x[n,:] . u_src[h,:] ; a_dst likewise. 64 nodes/block.
__global__ __launch_bounds__(256) void k_a(
    const float* __restrict__ x1, const float* __restrict__ x2,
    const float* __restrict__ u, float* __restrict__ asrc, float* __restrict__ adst) {
  int graph = blockIdx.y;
  const float* x = graph ? x2 : x1;
  const float* ug = u + graph * 2048;
  __shared__ float xs[64][129];
  __shared__ float us[16][128];
  int t = threadIdx.x;
  for (int i = t; i < 2048; i += 256) us[i >> 7][i & 127] = ug[i];
  int n0 = blockIdx.x * 64;
  const float* xb = x + (size_t)n0 * 128;
  for (int i = t; i < 64 * 128; i += 256) xs[i >> 7][i & 127] = xb[i];
  __syncthreads();
  int nl = t & 63;
  int j0 = (t >> 6) * 4;
  float a0 = 0.f, a1 = 0.f, a2 = 0.f, a3 = 0.f;
#pragma unroll 4
  for (int k = 0; k < 128; ++k) {
    float xv = xs[nl][k];
    a0 += xv * us[j0 + 0][k];
    a1 += xv * us[j0 + 1][k];
    a2 += xv * us[j0 + 2][k];
    a3 += xv * us[j0 + 3][k];
  }
  int n = n0 + nl;
  float* outp = (j0 < 8) ? (asrc + graph * (NN * 8) + n * 8 + j0)
                         : (adst + graph * (NN * 8) + n * 8 + (j0 - 8));
  outp[0] = a0; outp[1] = a1; outp[2] = a2; outp[3] = a3;
}

// K3: histogram by dst and by src (self-loops are edges [EE,ET) with s=d).
__global__ __launch_bounds__(256) void k_count(
    const int* __restrict__ ei1, const int* __restrict__ ei2, int* __restrict__ cnt) {
  int g = blockIdx.y;
  const int* ei = g ? ei2 : ei1;
  int idx = blockIdx.x * 256 + threadIdx.x;
  if (idx >= ET) return;
  int s, d;
  if (idx < EE) { s = ei[idx]; d = ei[EE + idx]; } else { s = d = idx - EE; }
  atomicAdd(cnt + (2 * g + 0) * NN + d, 1);
  atomicAdd(cnt + (2 * g + 1) * NN + s, 1);
}

// K4: exclusive prefix scan of one 8192-int histogram per block (4 blocks).
__global__ __launch_bounds__(1024) void k_scan(
    const int* __restrict__ cnt, int* __restrict__ cur, int* __restrict__ off) {
  int b = blockIdx.x;                  // 0..3 : (graph,dir)
  const int* c = cnt + b * NN;
  int* cu = cur + b * NN;
  int* of = off + b * OFFPAD;
  __shared__ int sums[1024];
  int t = threadIdx.x;
  int base = t * 8;
  int loc[8];
  int s = 0;
#pragma unroll
  for (int i = 0; i < 8; ++i) { loc[i] = s; s += c[base + i]; }
  sums[t] = s;
  __syncthreads();
  for (int o = 1; o < 1024; o <<= 1) {
    int v = (t >= o) ? sums[t - o] : 0;
    __syncthreads();
    sums[t] += v;
    __syncthreads();
  }
  int excl = t ? sums[t - 1] : 0;
#pragma unroll
  for (int i = 0; i < 8; ++i) {
    int v = excl + loc[i];
    of[base + i] = v;
    cu[base + i] = v;
  }
  if (t == 1023) of[NN] = sums[1023];
}

// K5: scatter edges into dst-sorted (payload src) and src-sorted (payload dst) arrays.
__global__ __launch_bounds__(256) void k_scatter(
    const int* __restrict__ ei1, const int* __restrict__ ei2,
    int* __restrict__ cur, int* __restrict__ sorted) {
  int g = blockIdx.y;
  const int* ei = g ? ei2 : ei1;
  int idx = blockIdx.x * 256 + threadIdx.x;
  if (idx >= ET) return;
  int s, d;
  if (idx < EE) { s = ei[idx]; d = ei[EE + idx]; } else { s = d = idx - EE; }
  int pD = atomicAdd(cur + (2 * g + 0) * NN + d, 1);
  sorted[(size_t)(2 * g + 0) * ET + pD] = s;
  int pS = atomicAdd(cur + (2 * g + 1) * NN + s, 1);
  sorted[(size_t)(2 * g + 1) * ET + pS] = d;
}

// K6: rden[d,h] = 1 / sum_{e:dst=d} exp(lrelu(asrc[src]+adst[d])).  Wave per dst,
// lane = (edge_octet, head): gathers are 32B-coalesced, reduce = 3 shfl_xor.
__global__ __launch_bounds__(256) void k_den(
    const int* __restrict__ off, const int* __restrict__ sorted,
    const float* __restrict__ asrc, const float* __restrict__ adst,
    float* __restrict__ rden) {
  int g = blockIdx.y;
  int d = blockIdx.x * 4 + (threadIdx.x >> 6);
  int lane = threadIdx.x & 63;
  int h = lane & 7, eo = lane >> 3;
  const int* of = off + (2 * g + 0) * OFFPAD;
  const int* st = sorted + (size_t)(2 * g + 0) * ET;
  const float* as = asrc + g * (NN * 8);
  const float* ad = adst + g * (NN * 8);
  int lo = of[d], hi = of[d + 1];
  float adv = ad[d * 8 + h];
  float acc = 0.f;
  for (int i = lo + eo; i < hi; i += 8) {
    int s = st[i];
    float v = as[s * 8 + h] + adv;
    v = v > 0.f ? v : NEG * v;
    acc += __expf(v);
  }
  acc += __shfl_xor(acc, 8);
  acc += __shfl_xor(acc, 16);
  acc += __shfl_xor(acc, 32);
  if (eo == 0) rden[g * (NN * 8) + d * 8 + h] = 1.0f / acc;
}

// K7: w[s,h] = sum_{e:src=s} exp(lrelu(asrc[s]+adst[d])) * rden[d].  Wave per src.
__global__ __launch_bounds__(256) void k_wacc(
    const int* __restrict__ off, const int* __restrict__ sorted,
    const float* __restrict__ asrc, const float* __restrict__ adst,
    const float* __restrict__ rden, float* __restrict__ wacc) {
  int g = blockIdx.y;
  int sn = blockIdx.x * 4 + (threadIdx.x >> 6);
  int lane = threadIdx.x & 63;
  int h = lane & 7, eo = lane >> 3;
  const int* of = off + (2 * g + 1) * OFFPAD;
  const int* st = sorted + (size_t)(2 * g + 1) * ET;
  const float* as = asrc + g * (NN * 8);
  const float* ad = adst + g * (NN * 8);
  const float* rd = rden + g * (NN * 8);
  int lo = of[sn], hi = of[sn + 1];
  float asv = as[sn * 8 + h];
  float acc = 0.f;
  for (int i = lo + eo; i < hi; i += 8) {
    int d = st[i];
    float v = asv + ad[d * 8 + h];
    v = v > 0.f ? v : NEG * v;
    acc += __expf(v) * rd[d * 8 + h];
  }
  acc += __shfl_xor(acc, 8);
  acc += __shfl_xor(acc, 16);
  acc += __shfl_xor(acc, 32);
  if (eo == 0) wacc[g * (NN * 8) + sn * 8 + h] = acc;
}

// K8: g[head,k] = sum_n w[n,head] * x[n,k].
#define GCHUNK 128
__global__ __launch_bounds__(256) void k_gred(
    const float* __restrict__ x1, const float* __restrict__ x2,
    const float* __restrict__ wacc, float* __restrict__ g) {
  int graph = blockIdx.y;
  const float* x = graph ? x2 : x1;
  const float* w = wacc + graph * (NN * 8);
  float* gg = g + graph * 1024;
  int t = threadIdx.x;
  int k = t & 127;
  int h0 = (t >> 7) * 4;
  int n0 = blockIdx.x * GCHUNK;
  float a0 = 0.f, a1 = 0.f, a2 = 0.f, a3 = 0.f;
#pragma unroll 4
  for (int n = n0; n < n0 + GCHUNK; ++n) {
    float xv = x[(size_t)n * 128 + k];
    float4 wv = *(const float4*)(w + (size_t)n * 8 + h0);
    a0 += xv * wv.x; a1 += xv * wv.y; a2 += xv * wv.z; a3 += xv * wv.w;
  }
  atomicAdd(gg + (h0 + 0) * 128 + k, a0);
  atomicAdd(gg + (h0 + 1) * 128 + k, a1);
  atomicAdd(gg + (h0 + 2) * 128 + k, a2);
  atomicAdd(gg + (h0 + 3) * 128 + k, a3);
}

// K9: memb[graph][e] = (1/N) * sum_k g[head,k]*W[k*1024+e] + b[e]
__global__ __launch_bounds__(256) void k_memb(
    const float* __restrict__ W1, const float* __restrict__ W2,
    const float* __restrict__ b1, const float* __restrict__ b2,
    const float* __restrict__ g, float* __restrict__ memb) {
  int graph = blockIdx.y;
  const float* W = graph ? W2 : W1;
  const float* b = graph ? b2 : b1;
  const float* gg = g + graph * 1024;
  int e = blockIdx.x * 256 + threadIdx.x;
  int head = e >> 7;
  const float* gr = gg + head * 128;
  float s = 0.f;
#pragma unroll 4
  for (int k = 0; k < 128; ++k) s += gr[k] * W[(size_t)k * 1024 + e];
  memb[graph * 1024 + e] = s * (1.0f / (float)NN) + b[e];
}

// K10: out = [memb(g1); memb(g0)] @ Wl + bl, split-k over 32 blocks (out pre-zeroed).
__global__ __launch_bounds__(256) void k_out(
    const float* __restrict__ memb, const float* __restrict__ Wl,
    const float* __restrict__ bl, float* __restrict__ out) {
  int t = threadIdx.x;
  int j = t & 127;
  int k0 = blockIdx.x * 32;
  const float* m = (t < 128) ? (memb + 1024) : memb;
  float s = 0.f;
#pragma unroll
  for (int k = k0; k < k0 + 32; ++k) s += m[k] * Wl[(size_t)k * 128 + j];
  if (blockIdx.x == 0) s += bl[j];
  atomicAdd(out + t, s);
}

extern "C" void kernel_launch(void* const* d_in, const int* in_sizes, int n_in,
                              void* d_out, int out_size, void* d_ws, size_t ws_size,
                              hipStream_t stream) {
  const float* x1  = (const float*)d_in[0];
  const int*   ei1 = (const int*)d_in[1];
  const float* W1  = (const float*)d_in[2];
  const float* as1 = (const float*)d_in[3];
  const float* ad1 = (const float*)d_in[4];
  const float* b1  = (const float*)d_in[5];
  const float* x2  = (const float*)d_in[6];
  const int*   ei2 = (const int*)d_in[7];
  const float* W2  = (const float*)d_in[8];
  const float* as2 = (const float*)d_in[9];
  const float* ad2 = (const float*)d_in[10];
  const float* b2  = (const float*)d_in[11];
  const float* Wl  = (const float*)d_in[12];
  const float* bl  = (const float*)d_in[13];
  float* out = (float*)d_out;

  int*   cnt    = (int*)d_ws + U_CNT;
  float* g      = (float*)d_ws + U_G;
  int*   cur    = (int*)d_ws + U_CUR;
  int*   off    = (int*)d_ws + U_OFF;
  int*   sorted = (int*)d_ws + U_SORT;
  float* asrc   = (float*)d_ws + U_ASRC;
  float* adst   = (float*)d_ws + U_ADST;
  float* rden   = (float*)d_ws + U_RDEN;
  float* wacc   = (float*)d_ws + U_WACC;
  float* u      = (float*)d_ws + U_U;
  float* memb   = (float*)d_ws + U_MEMB;

  hipMemsetAsync(d_ws, 0, ZERO_BYTES, stream);             // cnt + g
  hipMemsetAsync(d_out, 0, (size_t)out_size * 4, stream);  // split-k target

  k_u<<<16, 256, 0, stream>>>(W1, as1, ad1, W2, as2, ad2, u);
  k_a<<<dim3(NN / 64, 2), 256, 0, stream>>>(x1, x2, u, asrc, adst);
  k_count<<<dim3((ET + 255) / 256, 2), 256, 0, stream>>>(ei1, ei2, cnt);
  k_scan<<<4, 1024, 0, stream>>>(cnt, cur, off);
  k_scatter<<<dim3((ET + 255) / 256, 2), 256, 0, stream>>>(ei1, ei2, cur, sorted);
  k_den<<<dim3(NN / 4, 2), 256, 0, stream>>>(off, sorted, asrc, adst, rden);
  k_wacc<<<dim3(NN / 4, 2), 256, 0, stream>>>(off, sorted, asrc, adst, rden, wacc);
  k_gred<<<dim3(NN / GCHUNK, 2), 256, 0, stream>>>(x1, x2, wacc, g);
  k_memb<<<dim3(4, 2), 256, 0, stream>>>(W1, W2, b1, b2, g, memb);
  k_out<<<32, 256, 0, stream>>>(memb, Wl, bl, out);
}